// Round 11
// baseline (148.225 us; speedup 1.0000x reference)
//
#include <hip/hip_runtime.h>

#define HW 1024
#define CC 256
#define NB 32
constexpr float INV_T = 1.0f / 0.07f;

typedef __attribute__((ext_vector_type(8))) short short8;
typedef __attribute__((ext_vector_type(4))) float f32x4;

__device__ __forceinline__ ushort f2bf(float x) {
    uint32_t u = __float_as_uint(x);
    uint32_t r = (u + 0x7fffu + ((u >> 16) & 1u)) >> 16;
    return (ushort)r;
}
__device__ __forceinline__ float bf2f(ushort h) {
    return __uint_as_float(((uint32_t)h) << 16);
}

__device__ __forceinline__ void gload16(const void* g, void* l) {
    __builtin_amdgcn_global_load_lds(
        (const __attribute__((address_space(1))) uint32_t*)g,
        (__attribute__((address_space(3))) uint32_t*)l, 16, 0, 0);
}

// ---------------- Convert + transpose: X[b][c][hw] f32 -> hi/lo[b][hw][c] bf16 ----------------
__global__ __launch_bounds__(256) void convert_kernel(const float* __restrict__ A,
                                                      const float* __restrict__ Bm,
                                                      ushort* __restrict__ Qhi,
                                                      ushort* __restrict__ Qlo,
                                                      ushort* __restrict__ Phi,
                                                      ushort* __restrict__ Plo) {
    int blk = blockIdx.x;
    int which = blk >= NB * 64;
    if (which) blk -= NB * 64;
    const float* X = which ? Bm : A;
    ushort* hi = which ? Phi : Qhi;
    ushort* lo = which ? Plo : Qlo;

    int b = blk >> 6;
    int tile = blk & 63;
    int c0 = (tile >> 4) * 64;
    int h0 = (tile & 15) * 64;

    __shared__ ushort Th[64][76];
    __shared__ ushort Tl[64][76];

    int tid = threadIdx.x;
    const float* Xb = X + ((size_t)b * CC + c0) * HW + h0;

#pragma unroll
    for (int p = 0; p < 4; ++p) {
        int cr = p * 16 + (tid >> 4);
        int hcol = (tid & 15) * 4;
        float4 v = *reinterpret_cast<const float4*>(&Xb[(size_t)cr * HW + hcol]);
        float xs[4] = {v.x, v.y, v.z, v.w};
#pragma unroll
        for (int j = 0; j < 4; ++j) {
            float x = xs[j];
            ushort h_ = f2bf(x);
            float hf = bf2f(h_);
            ushort l_ = f2bf(x - hf);
            Th[hcol + j][cr] = h_;
            Tl[hcol + j][cr] = l_;
        }
    }
    __syncthreads();
    size_t obase = ((size_t)b * HW + h0) * CC + c0;
#pragma unroll
    for (int q = 0; q < 4; ++q) {
        int hr = q * 16 + (tid >> 4);
        int cc = (tid & 15) * 4;
        ushort4 vh = *reinterpret_cast<const ushort4*>(&Th[hr][cc]);
        ushort4 vl = *reinterpret_cast<const ushort4*>(&Tl[hr][cc]);
        *reinterpret_cast<ushort4*>(&hi[obase + (size_t)hr * CC + cc]) = vh;
        *reinterpret_cast<ushort4*>(&lo[obase + (size_t)hr * CC + cc]) = vl;
    }
}

// ---- stage one BK=32 panel chunk (128 rows x 64B) into an 8KB LDS panel; 512 threads ----
// LDS: [64 ldsrows][128B]; global row r -> ldsrow r&63, byte bit6 = r>>6; XOR ((ldsrow&7)<<4)
__device__ __forceinline__ void stage32(const char* g, char* lbase, int tid, int w) {
    int o = tid * 16;
    int ldsrow = o >> 7;
    int ub = (o & 127) ^ ((ldsrow & 7) << 4);
    int grow = ldsrow + ((ub >> 6) << 6);
    gload16(g + grow * 512 + (ub & 63), lbase + w * 1024);
}

// ---------------- Kernel 1: split-bf16 MFMA GEMM, 128x128 tile, 8 waves, wave-tile 64x32 -----
// 32KB LDS + <=128 regs/wave -> 2 blocks/CU (16 waves/CU).
// Writes G'[b][i][col'] = bf16(exp(x - rtm)), fragment-native col' permutation within 32-blocks:
//   value for k = kblk*32 + fj*16 + l15 stored at col' = kblk*32 + l15*2 + fj.
__global__ __launch_bounds__(512, 4) void gemm_mfma(const ushort* __restrict__ Phi,
                                                    const ushort* __restrict__ Plo,
                                                    const ushort* __restrict__ Qhi,
                                                    const ushort* __restrict__ Qlo,
                                                    ushort* __restrict__ G,
                                                    float* __restrict__ rpm,
                                                    float* __restrict__ rps,
                                                    float* __restrict__ cpm,
                                                    float* __restrict__ cps) {
    int bid = blockIdx.x;
    int swz = (bid & 7) * 256 + (bid >> 3);   // XCD swizzle, 2048 % 8 == 0 -> bijective
    int b = swz >> 6;
    int tile = swz & 63;
    int i0 = (tile >> 3) << 7;
    int k0 = (tile & 7) << 7;

    // panels: 0=Phi 1=Plo 2=Qhi 3=Qlo, each 8KB
    __shared__ char S[4][8192];

    int tid = threadIdx.x;
    int lane = tid & 63;
    int w = tid >> 6;                         // 0..7
    int wr = w >> 2, wc = w & 3;              // 2M x 4N; wave owns 64 rows x 32 cols
    int l15 = lane & 15, lg = lane >> 4;

    f32x4 acc[4][2];
#pragma unroll
    for (int fi = 0; fi < 4; ++fi)
#pragma unroll
        for (int fj = 0; fj < 2; ++fj)
#pragma unroll
            for (int r = 0; r < 4; ++r) acc[fi][fj][r] = 0.0f;

    size_t bbase = (size_t)b * HW * CC;
    const char* g0 = (const char*)(Phi + bbase + (size_t)i0 * CC);
    const char* g1 = (const char*)(Plo + bbase + (size_t)i0 * CC);
    const char* g2 = (const char*)(Qhi + bbase + (size_t)k0 * CC);
    const char* g3 = (const char*)(Qlo + bbase + (size_t)k0 * CC);

    // prologue: stage chunk 0
    stage32(g0, &S[0][0], tid, w);
    stage32(g1, &S[1][0], tid, w);
    stage32(g2, &S[2][0], tid, w);
    stage32(g3, &S[3][0], tid, w);

    for (int c = 0; c < 8; ++c) {
        __syncthreads();                     // stage(c) complete (vmcnt0 drain)

        // read this chunk's fragments (12 x ds_read_b128)
        short8 fPh[4], fPl[4], fQh[2], fQl[2];
#pragma unroll
        for (int f = 0; f < 4; ++f) {
            int rp = wr * 64 + f * 16 + l15;                     // 0..127
            int lr = rp & 63;
            int bp = ((((rp >> 6) << 6) + (lg << 4))) ^ ((lr & 7) << 4);
            fPh[f] = *(const short8*)(&S[0][0] + lr * 128 + bp);
            fPl[f] = *(const short8*)(&S[1][0] + lr * 128 + bp);
        }
#pragma unroll
        for (int f = 0; f < 2; ++f) {
            int rq = wc * 32 + f * 16 + l15;                     // 0..127
            int lq = rq & 63;
            int bq = ((((rq >> 6) << 6) + (lg << 4))) ^ ((lq & 7) << 4);
            fQh[f] = *(const short8*)(&S[2][0] + lq * 128 + bq);
            fQl[f] = *(const short8*)(&S[3][0] + lq * 128 + bq);
        }
        __syncthreads();                     // all reads done -> buffer reusable

        if (c < 7) {                         // stage next chunk; latency hidden by 24 MFMA below
            int co = (c + 1) * 64;           // 32 elems * 2B
            stage32(g0 + co, &S[0][0], tid, w);
            stage32(g1 + co, &S[1][0], tid, w);
            stage32(g2 + co, &S[2][0], tid, w);
            stage32(g3 + co, &S[3][0], tid, w);
        }

        // 24 MFMA from registers: hi*hi, hi*lo, lo*hi
#pragma unroll
        for (int fi = 0; fi < 4; ++fi)
#pragma unroll
            for (int fj = 0; fj < 2; ++fj)
                acc[fi][fj] = __builtin_amdgcn_mfma_f32_16x16x32_bf16(fPh[fi], fQh[fj], acc[fi][fj], 0, 0, 0);
#pragma unroll
        for (int fi = 0; fi < 4; ++fi)
#pragma unroll
            for (int fj = 0; fj < 2; ++fj)
                acc[fi][fj] = __builtin_amdgcn_mfma_f32_16x16x32_bf16(fPh[fi], fQl[fj], acc[fi][fj], 0, 0, 0);
#pragma unroll
        for (int fi = 0; fi < 4; ++fi)
#pragma unroll
            for (int fj = 0; fj < 2; ++fj)
                acc[fi][fj] = __builtin_amdgcn_mfma_f32_16x16x32_bf16(fPl[fi], fQh[fj], acc[fi][fj], 0, 0, 0);
    }

    // ---- fused epilogue: row partial stats (per 32-col block) + native-order G store ----
    int kt = (tile & 7) * 4 + wc;             // 0..31 col-block-of-32
    int it = (tile >> 3) * 2 + wr;            // 0..15 row-block-of-64
    size_t rbase = ((size_t)b * 32 + kt) * HW;
    size_t cbase = ((size_t)b * 16 + it) * HW;
    ushort* Gb = G + (size_t)b * HW * HW;
    int kcol2 = k0 + wc * 32 + l15 * 2;       // ushort2 store column

#pragma unroll
    for (int fi = 0; fi < 4; ++fi) {
#pragma unroll
        for (int r = 0; r < 4; ++r) {
            float x0 = acc[fi][0][r] * INV_T;
            float x1 = acc[fi][1][r] * INV_T;
            float m = fmaxf(x0, x1);
#pragma unroll
            for (int off = 1; off < 16; off <<= 1) m = fmaxf(m, __shfl_xor(m, off));
            float e0 = __expf(x0 - m), e1 = __expf(x1 - m);
            int i = i0 + wr * 64 + fi * 16 + (lg << 2) + r;
            ushort2 st;
            st.x = f2bf(e0);
            st.y = f2bf(e1);
            *reinterpret_cast<ushort2*>(&Gb[(size_t)i * HW + kcol2]) = st;
            float s = e0 + e1;
#pragma unroll
            for (int off = 1; off < 16; off <<= 1) s += __shfl_xor(s, off);
            if (l15 == 0) {
                rpm[rbase + i] = m;
                rps[rbase + i] = s;
            }
        }
    }

    // ---- fused col partial stats (wave's 64 rows per col) ----
#pragma unroll
    for (int fj = 0; fj < 2; ++fj) {
        float m = -INFINITY;
#pragma unroll
        for (int fi = 0; fi < 4; ++fi)
#pragma unroll
            for (int r = 0; r < 4; ++r) m = fmaxf(m, acc[fi][fj][r] * INV_T);
        m = fmaxf(m, __shfl_xor(m, 16));
        m = fmaxf(m, __shfl_xor(m, 32));
        float s = 0.f;
#pragma unroll
        for (int fi = 0; fi < 4; ++fi)
#pragma unroll
            for (int r = 0; r < 4; ++r) s += __expf(acc[fi][fj][r] * INV_T - m);
        s += __shfl_xor(s, 16);
        s += __shfl_xor(s, 32);
        if (lane < 16) {
            int k = k0 + wc * 32 + fj * 16 + lane;
            cpm[cbase + k] = m;
            cps[cbase + k] = s;
        }
    }
}

// ---------------- Kernel 2: combine partials (rows: 32, cols: 16) ----------------
__global__ __launch_bounds__(256) void combine_kernel(const float* __restrict__ rpm,
                                                      const float* __restrict__ rps,
                                                      const float* __restrict__ cpm,
                                                      const float* __restrict__ cps,
                                                      float* __restrict__ rmax,
                                                      float* __restrict__ rsuminv,
                                                      float* __restrict__ cmax,
                                                      float* __restrict__ csuminv) {
    int blk = blockIdx.x;
    int iscol = blk >= 128;
    if (iscol) blk -= 128;
    int idx = blk * 256 + threadIdx.x;
    int b = idx >> 10;
    int e = idx & 1023;
    const float* pm = iscol ? cpm : rpm;
    const float* ps = iscol ? cps : rps;
    int nt = iscol ? 16 : 32;
    size_t base = (size_t)b * nt * HW + e;
    float m = -INFINITY;
    for (int t = 0; t < nt; ++t) m = fmaxf(m, pm[base + (size_t)t * HW]);
    float s = 0.f;
    for (int t = 0; t < nt; ++t) s += ps[base + (size_t)t * HW] * __expf(pm[base + (size_t)t * HW] - m);
    if (iscol) {
        cmax[idx] = m;
        csuminv[idx] = 1.0f / s;
    } else {
        rmax[idx] = m;
        rsuminv[idx] = 1.0f / s;
    }
}

// ---------------- Kernel 3: P = G'^2 * clamp(exp(2*rtm - rm - cm)) * rsinv * csinv -----------
// G' is fragment-native: value for k = kblk*32 + fj*16 + l15 at col' = kblk*32 + l15*2 + fj.
__global__ __launch_bounds__(256) void final_kernel(const ushort* __restrict__ G,
                                                    const float* __restrict__ rpm,
                                                    const float* __restrict__ rm,
                                                    const float* __restrict__ rsi,
                                                    const float* __restrict__ cm,
                                                    const float* __restrict__ csi,
                                                    float* __restrict__ out) {
    int blk = blockIdx.x;
    int b = blk >> 8;
    int tile = blk & 255;
    int i0 = (tile >> 4) * 64;
    int k0 = (tile & 15) * 64;
    int kb = k0 >> 5;                         // first 32-block index
    const ushort* Gb = G + (size_t)b * HW * HW;
    float* outb = out + (size_t)b * HW * HW;
    const float* rpm0 = rpm + ((size_t)b * 32 + kb) * HW;
    const float* rpm1 = rpm0 + HW;
    const float* rmb = rm + b * HW;
    const float* rsib = rsi + b * HW;
    const float* cmb = cm + b * HW;
    const float* csib = csi + b * HW;

    __shared__ float tileP[64][65];

    int t = threadIdx.x;
    int tr = t >> 4;
    int tc = t & 15;

    // this thread's 4 true columns: k0 + tc + {0,16,32,48}
    float cmv[4], csv[4];
#pragma unroll
    for (int j = 0; j < 4; ++j) {
        cmv[j] = cmb[k0 + tc + j * 16];
        csv[j] = csib[k0 + tc + j * 16];
    }

#pragma unroll
    for (int rr = 0; rr < 4; ++rr) {
        int il = tr + rr * 16;
        int i = i0 + il;
        float rmv = rmb[i];
        float a0 = rpm0[i] + rpm0[i] - rmv;
        float a1 = rpm1[i] + rpm1[i] - rmv;
        float rsinv = rsib[i];
        ushort2 g01 = *reinterpret_cast<const ushort2*>(&Gb[(size_t)i * HW + k0 + tc * 2]);
        ushort2 g23 = *reinterpret_cast<const ushort2*>(&Gb[(size_t)i * HW + k0 + 32 + tc * 2]);
        float g[4] = {bf2f(g01.x), bf2f(g01.y), bf2f(g23.x), bf2f(g23.y)};
        float a[4] = {a0, a0, a1, a1};
#pragma unroll
        for (int j = 0; j < 4; ++j) {
            float e = fminf(__expf(a[j] - cmv[j]), 1e30f);
            tileP[il][tc + j * 16] = g[j] * g[j] * e * rsinv * csv[j];
        }
    }
    __syncthreads();
    int tc4 = tc * 4;
#pragma unroll
    for (int rr = 0; rr < 4; ++rr) {
        int kl = tr + rr * 16;
        int k = k0 + kl;
        int tk = ((k & 31) << 5) | (k >> 5);
        float4 v;
        v.x = tileP[tc4 + 0][kl];
        v.y = tileP[tc4 + 1][kl];
        v.z = tileP[tc4 + 2][kl];
        v.w = tileP[tc4 + 3][kl];
        *reinterpret_cast<float4*>(&outb[(size_t)tk * HW + i0 + tc4]) = v;
    }
}

extern "C" void kernel_launch(void* const* d_in, const int* in_sizes, int n_in,
                              void* d_out, int out_size, void* d_ws, size_t ws_size,
                              hipStream_t stream) {
    const float* A = (const float*)d_in[0];   // feature_A [32,256,32,32]
    const float* Bm = (const float*)d_in[1];  // feature_B [32,256,32,32]
    float* out = (float*)d_out;

    const size_t n_elems = (size_t)NB * HW * HW;       // 33.5M
    const size_t stat_n = (size_t)NB * HW;             // 32768
    const size_t rpart_n = (size_t)NB * 32 * HW;       // 1048576
    const size_t cpart_n = (size_t)NB * 16 * HW;       // 524288
    ushort* G = (ushort*)d_ws;                         // 67 MB
    float* fbase = (float*)(G + n_elems);
    float* rmax = fbase;
    float* rsuminv = rmax + stat_n;
    float* cmax = rsuminv + stat_n;
    float* csuminv = cmax + stat_n;
    float* rpm = csuminv + stat_n;
    float* rps = rpm + rpart_n;
    float* cpm = rps + rpart_n;
    float* cps = cpm + cpart_n;
    ushort* Qhi = (ushort*)(cps + cpart_n);
    ushort* Qlo = Qhi + (size_t)NB * HW * CC;
    ushort* Phi = Qlo + (size_t)NB * HW * CC;
    ushort* Plo = Phi + (size_t)NB * HW * CC;

    hipLaunchKernelGGL(convert_kernel, dim3(2 * NB * 64), dim3(256), 0, stream,
                       A, Bm, Qhi, Qlo, Phi, Plo);
    hipLaunchKernelGGL(gemm_mfma, dim3(NB * 64), dim3(512), 0, stream,
                       Phi, Plo, Qhi, Qlo, G, rpm, rps, cpm, cps);
    hipLaunchKernelGGL(combine_kernel, dim3(256), dim3(256), 0, stream,
                       rpm, rps, cpm, cps, rmax, rsuminv, cmax, csuminv);
    hipLaunchKernelGGL(final_kernel, dim3(NB * 256), dim3(256), 0, stream,
                       G, rpm, rmax, rsuminv, cmax, csuminv, out);
}

// Round 12
// 127.670 us; speedup vs baseline: 1.1610x; 1.1610x over previous
//
#include <hip/hip_runtime.h>

#define HW 1024
#define CC 256
#define NB 32
constexpr float INV_T = 1.0f / 0.07f;

typedef __attribute__((ext_vector_type(8))) short short8;
typedef __attribute__((ext_vector_type(4))) float f32x4;

__device__ __forceinline__ ushort f2bf(float x) {
    uint32_t u = __float_as_uint(x);
    uint32_t r = (u + 0x7fffu + ((u >> 16) & 1u)) >> 16;
    return (ushort)r;
}
__device__ __forceinline__ float bf2f(ushort h) {
    return __uint_as_float(((uint32_t)h) << 16);
}

__device__ __forceinline__ void gload16(const void* g, void* l) {
    __builtin_amdgcn_global_load_lds(
        (const __attribute__((address_space(1))) uint32_t*)g,
        (__attribute__((address_space(3))) uint32_t*)l, 16, 0, 0);
}

// ---------------- Convert + transpose: X[b][c][hw] f32 -> hi/lo[b][hw][c] bf16 ----------------
__global__ __launch_bounds__(256) void convert_kernel(const float* __restrict__ A,
                                                      const float* __restrict__ Bm,
                                                      ushort* __restrict__ Qhi,
                                                      ushort* __restrict__ Qlo,
                                                      ushort* __restrict__ Phi,
                                                      ushort* __restrict__ Plo) {
    int blk = blockIdx.x;
    int which = blk >= NB * 64;
    if (which) blk -= NB * 64;
    const float* X = which ? Bm : A;
    ushort* hi = which ? Phi : Qhi;
    ushort* lo = which ? Plo : Qlo;

    int b = blk >> 6;
    int tile = blk & 63;
    int c0 = (tile >> 4) * 64;
    int h0 = (tile & 15) * 64;

    __shared__ ushort Th[64][76];
    __shared__ ushort Tl[64][76];

    int tid = threadIdx.x;
    const float* Xb = X + ((size_t)b * CC + c0) * HW + h0;

#pragma unroll
    for (int p = 0; p < 4; ++p) {
        int cr = p * 16 + (tid >> 4);
        int hcol = (tid & 15) * 4;
        float4 v = *reinterpret_cast<const float4*>(&Xb[(size_t)cr * HW + hcol]);
        float xs[4] = {v.x, v.y, v.z, v.w};
#pragma unroll
        for (int j = 0; j < 4; ++j) {
            float x = xs[j];
            ushort h_ = f2bf(x);
            float hf = bf2f(h_);
            ushort l_ = f2bf(x - hf);
            Th[hcol + j][cr] = h_;
            Tl[hcol + j][cr] = l_;
        }
    }
    __syncthreads();
    size_t obase = ((size_t)b * HW + h0) * CC + c0;
#pragma unroll
    for (int q = 0; q < 4; ++q) {
        int hr = q * 16 + (tid >> 4);
        int cc = (tid & 15) * 4;
        ushort4 vh = *reinterpret_cast<const ushort4*>(&Th[hr][cc]);
        ushort4 vl = *reinterpret_cast<const ushort4*>(&Tl[hr][cc]);
        *reinterpret_cast<ushort4*>(&hi[obase + (size_t)hr * CC + cc]) = vh;
        *reinterpret_cast<ushort4*>(&lo[obase + (size_t)hr * CC + cc]) = vl;
    }
}

// ---- stage one BK=32 panel chunk (128 rows x 64B) into an 8KB LDS panel; 256 threads ----
// LDS layout: [64 ldsrows][128B]; global row r -> ldsrow r&63, byte-hi bit (r>>6)*64;
// bytes XOR-swizzled with ((ldsrow&7)<<4). gload16 dest must be wave-uniform base.
__device__ __forceinline__ void stage32(const char* g, char* lbase, int tid, int w) {
#pragma unroll
    for (int it = 0; it < 2; ++it) {
        int o = it * 4096 + tid * 16;                 // this lane's dest linear offset
        int ldsrow = o >> 7;
        int ub = (o & 127) ^ ((ldsrow & 7) << 4);     // unswizzled byte-in-row
        int grow = ldsrow + ((ub >> 6) << 6);         // global row 0..127
        int gcol = ub & 63;                           // byte col in 64B chunk row
        gload16(g + grow * 512 + gcol, lbase + it * 4096 + w * 1024);
    }
}

// ---------------- Kernel 1: split-bf16 MFMA GEMM, BK=32, single 32KB buffer ----------------
// Writes G'[b][i][col'] = bf16(exp(x - rtm(i,64-col-block))), fragment-native permutation:
//   value for k = kb*32 + fj2*16 + l15 stored at col' = kb*32 + l15*2 + fj2.
__global__ __launch_bounds__(256, 2) void gemm_mfma(const ushort* __restrict__ Phi,
                                                    const ushort* __restrict__ Plo,
                                                    const ushort* __restrict__ Qhi,
                                                    const ushort* __restrict__ Qlo,
                                                    ushort* __restrict__ G,
                                                    float* __restrict__ rpm,
                                                    float* __restrict__ rps,
                                                    float* __restrict__ cpm,
                                                    float* __restrict__ cps) {
    int bid = blockIdx.x;
    int swz = (bid & 7) * 256 + (bid >> 3);   // XCD swizzle, 2048 % 8 == 0 -> bijective
    int b = swz >> 6;
    int tile = swz & 63;
    int i0 = (tile >> 3) << 7;
    int k0 = (tile & 7) << 7;

    // panels: 0=Phi 1=Plo 2=Qhi 3=Qlo, each 8KB
    __shared__ char S[4][8192];

    int tid = threadIdx.x;
    int lane = tid & 63;
    int w = tid >> 6;
    int wr = w >> 1, wc = w & 1;

    f32x4 acc[4][4];
#pragma unroll
    for (int fi = 0; fi < 4; ++fi)
#pragma unroll
        for (int fj = 0; fj < 4; ++fj)
#pragma unroll
            for (int r = 0; r < 4; ++r) acc[fi][fj][r] = 0.0f;

    size_t bbase = (size_t)b * HW * CC;
    const char* g0 = (const char*)(Phi + bbase + (size_t)i0 * CC);
    const char* g1 = (const char*)(Plo + bbase + (size_t)i0 * CC);
    const char* g2 = (const char*)(Qhi + bbase + (size_t)k0 * CC);
    const char* g3 = (const char*)(Qlo + bbase + (size_t)k0 * CC);

    // prologue: stage chunk 0
    stage32(g0, &S[0][0], tid, w);
    stage32(g1, &S[1][0], tid, w);
    stage32(g2, &S[2][0], tid, w);
    stage32(g3, &S[3][0], tid, w);

    for (int c = 0; c < 8; ++c) {
        __syncthreads();                     // stage(c) complete (vmcnt0 drain)

        // read this chunk's fragments (16 x ds_read_b128)
        short8 fPh[4], fPl[4], fQh[4], fQl[4];
#pragma unroll
        for (int f = 0; f < 4; ++f) {
            int rl = f * 16 + (lane & 15);                       // ldsrow
            int sw = (rl & 7) << 4;
            int bp = ((wr << 6) + ((lane >> 4) << 4)) ^ sw;
            fPh[f] = *(const short8*)(&S[0][0] + rl * 128 + bp);
            fPl[f] = *(const short8*)(&S[1][0] + rl * 128 + bp);
            int bq = ((wc << 6) + ((lane >> 4) << 4)) ^ sw;
            fQh[f] = *(const short8*)(&S[2][0] + rl * 128 + bq);
            fQl[f] = *(const short8*)(&S[3][0] + rl * 128 + bq);
        }
        __syncthreads();                     // all reads done -> buffer reusable

        if (c < 7) {                         // stage next chunk; latency hidden by 48 MFMA below
            int co = (c + 1) * 64;           // 32 elems * 2B
            stage32(g0 + co, &S[0][0], tid, w);
            stage32(g1 + co, &S[1][0], tid, w);
            stage32(g2 + co, &S[2][0], tid, w);
            stage32(g3 + co, &S[3][0], tid, w);
        }

        // 48 MFMA from registers: hi*hi, hi*lo, lo*hi
        __builtin_amdgcn_s_setprio(1);
#pragma unroll
        for (int fi = 0; fi < 4; ++fi)
#pragma unroll
            for (int fj = 0; fj < 4; ++fj)
                acc[fi][fj] = __builtin_amdgcn_mfma_f32_16x16x32_bf16(fPh[fi], fQh[fj], acc[fi][fj], 0, 0, 0);
#pragma unroll
        for (int fi = 0; fi < 4; ++fi)
#pragma unroll
            for (int fj = 0; fj < 4; ++fj)
                acc[fi][fj] = __builtin_amdgcn_mfma_f32_16x16x32_bf16(fPh[fi], fQl[fj], acc[fi][fj], 0, 0, 0);
#pragma unroll
        for (int fi = 0; fi < 4; ++fi)
#pragma unroll
            for (int fj = 0; fj < 4; ++fj)
                acc[fi][fj] = __builtin_amdgcn_mfma_f32_16x16x32_bf16(fPl[fi], fQh[fj], acc[fi][fj], 0, 0, 0);
        __builtin_amdgcn_s_setprio(0);
    }

    // ---- fused epilogue: row partial stats + fragment-native ushort2 G stores ----
    int kt = (tile & 7) * 2 + wc;
    int it = (tile >> 3) * 2 + wr;
    size_t rbase = ((size_t)b * 16 + kt) * HW;
    size_t cbase = ((size_t)b * 16 + it) * HW;
    ushort* Gb = G + (size_t)b * HW * HW;
    int l15 = lane & 15, lg = lane >> 4;
    int kcol2 = k0 + wc * 64 + l15 * 2;       // ushort2 store column (first 32-block)

#pragma unroll
    for (int fi = 0; fi < 4; ++fi) {
#pragma unroll
        for (int r = 0; r < 4; ++r) {
            float x0 = acc[fi][0][r] * INV_T;
            float x1 = acc[fi][1][r] * INV_T;
            float x2 = acc[fi][2][r] * INV_T;
            float x3 = acc[fi][3][r] * INV_T;
            float m = fmaxf(fmaxf(x0, x1), fmaxf(x2, x3));
#pragma unroll
            for (int off = 1; off < 16; off <<= 1) m = fmaxf(m, __shfl_xor(m, off));
            float e0 = __expf(x0 - m), e1 = __expf(x1 - m);
            float e2 = __expf(x2 - m), e3 = __expf(x3 - m);
            int i = i0 + wr * 64 + fi * 16 + (lg << 2) + r;
            ushort2 sa, sb;
            sa.x = f2bf(e0); sa.y = f2bf(e1);
            sb.x = f2bf(e2); sb.y = f2bf(e3);
            *reinterpret_cast<ushort2*>(&Gb[(size_t)i * HW + kcol2]) = sa;
            *reinterpret_cast<ushort2*>(&Gb[(size_t)i * HW + kcol2 + 32]) = sb;
            float s = e0 + e1 + e2 + e3;
#pragma unroll
            for (int off = 1; off < 16; off <<= 1) s += __shfl_xor(s, off);
            if (l15 == 0) {
                rpm[rbase + i] = m;
                rps[rbase + i] = s;
            }
        }
    }

    // ---- fused col partial stats ----
#pragma unroll
    for (int fj = 0; fj < 4; ++fj) {
        float m = -INFINITY;
#pragma unroll
        for (int fi = 0; fi < 4; ++fi)
#pragma unroll
            for (int r = 0; r < 4; ++r) m = fmaxf(m, acc[fi][fj][r] * INV_T);
        m = fmaxf(m, __shfl_xor(m, 16));
        m = fmaxf(m, __shfl_xor(m, 32));
        float s = 0.f;
#pragma unroll
        for (int fi = 0; fi < 4; ++fi)
#pragma unroll
            for (int r = 0; r < 4; ++r) s += __expf(acc[fi][fj][r] * INV_T - m);
        s += __shfl_xor(s, 16);
        s += __shfl_xor(s, 32);
        if (lane < 16) {
            int k = k0 + wc * 64 + fj * 16 + lane;
            cpm[cbase + k] = m;
            cps[cbase + k] = s;
        }
    }
}

// ---------------- Kernel 2: combine partials (16 row-partials, 16 col-partials) -------------
__global__ __launch_bounds__(256) void combine_kernel(const float* __restrict__ rpm,
                                                      const float* __restrict__ rps,
                                                      const float* __restrict__ cpm,
                                                      const float* __restrict__ cps,
                                                      float* __restrict__ rmax,
                                                      float* __restrict__ rsuminv,
                                                      float* __restrict__ cmax,
                                                      float* __restrict__ csuminv) {
    int blk = blockIdx.x;
    int iscol = blk >= 128;
    if (iscol) blk -= 128;
    int idx = blk * 256 + threadIdx.x;
    int b = idx >> 10;
    int e = idx & 1023;
    const float* pm = iscol ? cpm : rpm;
    const float* ps = iscol ? cps : rps;
    size_t base = (size_t)b * 16 * HW + e;
    float m = -INFINITY;
#pragma unroll
    for (int t = 0; t < 16; ++t) m = fmaxf(m, pm[base + (size_t)t * HW]);
    float s = 0.f;
#pragma unroll
    for (int t = 0; t < 16; ++t) s += ps[base + (size_t)t * HW] * __expf(pm[base + (size_t)t * HW] - m);
    if (iscol) {
        cmax[idx] = m;
        csuminv[idx] = 1.0f / s;
    } else {
        rmax[idx] = m;
        rsuminv[idx] = 1.0f / s;
    }
}

// ---------------- Kernel 3: P = G'^2 * clamp(exp(2*rtm - rm - cm)) * rsinv * csinv -----------
// G' fragment-native: value for k = kb*32 + fj2*16 + l15 at col' = kb*32 + l15*2 + fj2.
// rpm blocks are per-64-cols (16 per batch).
__global__ __launch_bounds__(256) void final_kernel(const ushort* __restrict__ G,
                                                    const float* __restrict__ rpm,
                                                    const float* __restrict__ rm,
                                                    const float* __restrict__ rsi,
                                                    const float* __restrict__ cm,
                                                    const float* __restrict__ csi,
                                                    float* __restrict__ out) {
    int blk = blockIdx.x;
    int b = blk >> 8;
    int tile = blk & 255;
    int i0 = (tile >> 4) * 64;
    int k0 = (tile & 15) * 64;
    int kt = k0 >> 6;
    const ushort* Gb = G + (size_t)b * HW * HW;
    float* outb = out + (size_t)b * HW * HW;
    const float* rpmb = rpm + ((size_t)b * 16 + kt) * HW;
    const float* rmb = rm + b * HW;
    const float* rsib = rsi + b * HW;
    const float* cmb = cm + b * HW;
    const float* csib = csi + b * HW;

    __shared__ float tileP[64][65];

    int t = threadIdx.x;
    int tr = t >> 4;
    int tc = t & 15;

    // this thread's 4 true columns: k0 + tc + {0,16,32,48}
    float cmv[4], csv[4];
#pragma unroll
    for (int j = 0; j < 4; ++j) {
        cmv[j] = cmb[k0 + tc + j * 16];
        csv[j] = csib[k0 + tc + j * 16];
    }

#pragma unroll
    for (int rr = 0; rr < 4; ++rr) {
        int il = tr + rr * 16;
        int i = i0 + il;
        float rtm = rpmb[i];
        float a = rtm + rtm - rmb[i];
        float rsinv = rsib[i];
        ushort2 g01 = *reinterpret_cast<const ushort2*>(&Gb[(size_t)i * HW + k0 + tc * 2]);
        ushort2 g23 = *reinterpret_cast<const ushort2*>(&Gb[(size_t)i * HW + k0 + 32 + tc * 2]);
        float g[4] = {bf2f(g01.x), bf2f(g01.y), bf2f(g23.x), bf2f(g23.y)};
#pragma unroll
        for (int j = 0; j < 4; ++j) {
            float e = fminf(__expf(a - cmv[j]), 1e30f);
            tileP[il][tc + j * 16] = g[j] * g[j] * e * rsinv * csv[j];
        }
    }
    __syncthreads();
    int tc4 = tc * 4;
#pragma unroll
    for (int rr = 0; rr < 4; ++rr) {
        int kl = tr + rr * 16;
        int k = k0 + kl;
        int tk = ((k & 31) << 5) | (k >> 5);
        float4 v;
        v.x = tileP[tc4 + 0][kl];
        v.y = tileP[tc4 + 1][kl];
        v.z = tileP[tc4 + 2][kl];
        v.w = tileP[tc4 + 3][kl];
        *reinterpret_cast<float4*>(&outb[(size_t)tk * HW + i0 + tc4]) = v;
    }
}

extern "C" void kernel_launch(void* const* d_in, const int* in_sizes, int n_in,
                              void* d_out, int out_size, void* d_ws, size_t ws_size,
                              hipStream_t stream) {
    const float* A = (const float*)d_in[0];   // feature_A [32,256,32,32]
    const float* Bm = (const float*)d_in[1];  // feature_B [32,256,32,32]
    float* out = (float*)d_out;

    const size_t n_elems = (size_t)NB * HW * HW;       // 33.5M
    const size_t stat_n = (size_t)NB * HW;             // 32768
    const size_t part_n = (size_t)NB * 16 * HW;        // 524288
    ushort* G = (ushort*)d_ws;                         // 67 MB
    float* fbase = (float*)(G + n_elems);
    float* rmax = fbase;
    float* rsuminv = rmax + stat_n;
    float* cmax = rsuminv + stat_n;
    float* csuminv = cmax + stat_n;
    float* rpm = csuminv + stat_n;
    float* rps = rpm + part_n;
    float* cpm = rps + part_n;
    float* cps = cpm + part_n;
    ushort* Qhi = (ushort*)(cps + part_n);
    ushort* Qlo = Qhi + (size_t)NB * HW * CC;
    ushort* Phi = Qlo + (size_t)NB * HW * CC;
    ushort* Plo = Phi + (size_t)NB * HW * CC;

    hipLaunchKernelGGL(convert_kernel, dim3(2 * NB * 64), dim3(256), 0, stream,
                       A, Bm, Qhi, Qlo, Phi, Plo);
    hipLaunchKernelGGL(gemm_mfma, dim3(NB * 64), dim3(256), 0, stream,
                       Phi, Plo, Qhi, Qlo, G, rpm, rps, cpm, cps);
    hipLaunchKernelGGL(combine_kernel, dim3(256), dim3(256), 0, stream,
                       rpm, rps, cpm, cps, rmax, rsuminv, cmax, csuminv);
    hipLaunchKernelGGL(final_kernel, dim3(NB * 256), dim3(256), 0, stream,
                       G, rpm, rmax, rsuminv, cmax, csuminv, out);
}